// Round 9
// baseline (377.848 us; speedup 1.0000x reference)
//
#include <hip/hip_runtime.h>
#include <hip/hip_bf16.h>

#define B_ 2
#define S_ 2048
#define D_ 1024
#define H_ 16
#define HD_ 64

typedef short bf16x8 __attribute__((ext_vector_type(8)));
typedef float f32x4 __attribute__((ext_vector_type(4)));

__device__ __forceinline__ f32x4 mfma16(bf16x8 a, bf16x8 b, f32x4 c) {
    return __builtin_amdgcn_mfma_f32_16x16x32_bf16(a, b, c, 0, 0, 0);
}

__device__ __forceinline__ bf16x8 ldb8(const __hip_bfloat16* p) {
    return *reinterpret_cast<const bf16x8*>(p);
}

// ---------------- fp32 -> bf16 conversion ----------------
__global__ __launch_bounds__(256) void conv_kernel(const float* __restrict__ src,
                                                   __hip_bfloat16* __restrict__ dst, int n4) {
    int i = blockIdx.x * 256 + threadIdx.x;
    if (i >= n4) return;
    float4 f = reinterpret_cast<const float4*>(src)[i];
    union { __hip_bfloat16 h[4]; ushort4 u; } cv;
    cv.h[0] = __float2bfloat16(f.x);
    cv.h[1] = __float2bfloat16(f.y);
    cv.h[2] = __float2bfloat16(f.z);
    cv.h[3] = __float2bfloat16(f.w);
    reinterpret_cast<ushort4*>(dst)[i] = cv.u;
}

// ---------------- GEMM: Y = X @ W^T + bias ----------------
// Staging with full-row 64B segments: lane l loads row l>>2, elems (l&3)*8.
template <int MODE>
__global__ __launch_bounds__(256) void gemm_bt(
    const __hip_bfloat16* __restrict__ X, const __hip_bfloat16* __restrict__ Wt,
    const float* __restrict__ bias0, const float* __restrict__ bias1,
    const float* __restrict__ bias2,
    __hip_bfloat16* __restrict__ Yq, __hip_bfloat16* __restrict__ Yk,
    __hip_bfloat16* __restrict__ Yv, float* __restrict__ Yo,
    int M, int N, int K) {
    __shared__ __hip_bfloat16 As[128][40];
    __shared__ __hip_bfloat16 Bs[128][40];

    const int ntn = N >> 7;
    const int tm = blockIdx.x / ntn;
    const int tn = blockIdx.x % ntn;
    const int t = threadIdx.x;
    const int w = t >> 6, l = t & 63, g = l >> 4, c = l & 15;
    const int wr = w >> 1, wc = w & 1;

    const int lrow = t >> 2;           // 0..63
    const int le0 = (t & 3) * 8;       // 0,8,16,24

    const size_t xrow0 = (size_t)(tm * 128 + lrow) * K;
    const size_t xrow1 = (size_t)(tm * 128 + 64 + lrow) * K;
    const size_t wrow0 = (size_t)(tn * 128 + lrow) * K;
    const size_t wrow1 = (size_t)(tn * 128 + 64 + lrow) * K;

    f32x4 acc[4][4] = {};

    for (int k0 = 0; k0 < K; k0 += 32) {
        __syncthreads();
        *reinterpret_cast<bf16x8*>(&As[lrow][le0])      = ldb8(&X[xrow0 + k0 + le0]);
        *reinterpret_cast<bf16x8*>(&As[64 + lrow][le0]) = ldb8(&X[xrow1 + k0 + le0]);
        *reinterpret_cast<bf16x8*>(&Bs[lrow][le0])      = ldb8(&Wt[wrow0 + k0 + le0]);
        *reinterpret_cast<bf16x8*>(&Bs[64 + lrow][le0]) = ldb8(&Wt[wrow1 + k0 + le0]);
        __syncthreads();

        bf16x8 am[4], bn[4];
#pragma unroll
        for (int mi = 0; mi < 4; ++mi) am[mi] = ldb8(&As[wr * 64 + mi * 16 + c][g * 8]);
#pragma unroll
        for (int ni = 0; ni < 4; ++ni) bn[ni] = ldb8(&Bs[wc * 64 + ni * 16 + c][g * 8]);
#pragma unroll
        for (int mi = 0; mi < 4; ++mi)
#pragma unroll
            for (int ni = 0; ni < 4; ++ni)
                acc[mi][ni] = mfma16(am[mi], bn[ni], acc[mi][ni]);
    }

#pragma unroll
    for (int mi = 0; mi < 4; ++mi) {
        const int mbase = tm * 128 + wr * 64 + mi * 16 + g * 4;
#pragma unroll
        for (int ni = 0; ni < 4; ++ni) {
            const int n = tn * 128 + wc * 64 + ni * 16 + c;
#pragma unroll
            for (int r = 0; r < 4; ++r) {
                const int mm = mbase + r;
                float v = acc[mi][ni][r];
                if (MODE == 0) {
                    const float* bp = (n < 1024) ? bias0 : (n < 2048) ? bias1 : bias2;
                    const int nn = n & 1023;
                    v += bp[nn];
                    const int b = mm >> 11, s = mm & 2047;
                    const int h = nn >> 6, hd = nn & 63;
                    const size_t bh = (size_t)(b * H_ + h);
                    const __hip_bfloat16 bvv = __float2bfloat16(v);
                    if (n < 2048) {
                        __hip_bfloat16* dst = (n < 1024) ? Yq : Yk;
                        dst[(bh * S_ + s) * HD_ + hd] = bvv;
                    } else {
                        Yv[(bh * HD_ + hd) * S_ + s] = bvv;
                    }
                } else {
                    Yo[(size_t)mm * N + n] = v + bias0[n];
                }
            }
        }
    }
}

// ---------------- fused attention: shared k-tiles staged in LDS ----------------
// grid: B*H*(S/32) blocks of 8 waves. Block owns 32 q-rows (groups A,B of 16).
// k iterates in 8 tiles of 256; per tile, 512 threads cooperatively stage
// K (pass1) / V (pass2) into XOR-swizzled LDS with coalesced global loads.
// Wave w owns the tile's k-window [32w, 32w+32); register-P~ algebra as r5-r7.
__global__ __launch_bounds__(512) void attn_kernel(
    const __hip_bfloat16* __restrict__ Qh, const __hip_bfloat16* __restrict__ Kh,
    const __hip_bfloat16* __restrict__ Vt, const float* __restrict__ mask,
    float* __restrict__ probs, __hip_bfloat16* __restrict__ ctx) {
    union SMem {
        struct { __hip_bfloat16 K[256 * 64]; __hip_bfloat16 V[64 * 256]; } kv;  // 64 KB
        float Cred[8][16][68];  // 34816 B (epilogue reuse)
    };
    __shared__ SMem sm;
    __shared__ float sred[8][32];
    __shared__ float invsh[32];

    const int blk = blockIdx.x;
    const int qt = blk & 63;         // S/32
    const int bh = blk >> 6;
    const int b = bh >> 4, h = bh & 15;
    const int t = threadIdx.x;
    const int w = t >> 6, l = t & 63, g = l >> 4, c = l & 15;
    const int q0 = qt * 32;
    const int kw = 32 * w;           // wave k-window within tile

    const __hip_bfloat16* Qb = Qh + (size_t)bh * S_ * HD_;
    const __hip_bfloat16* Kb = Kh + (size_t)bh * S_ * HD_;
    const __hip_bfloat16* Vb = Vt + (size_t)bh * HD_ * S_;
    const float* mrow = mask + (size_t)b * S_;

    const bf16x8 aqA0 = ldb8(&Qb[(q0 + c) * HD_ + g * 8]);
    const bf16x8 aqA1 = ldb8(&Qb[(q0 + c) * HD_ + 32 + g * 8]);
    const bf16x8 aqB0 = ldb8(&Qb[(q0 + 16 + c) * HD_ + g * 8]);
    const bf16x8 aqB1 = ldb8(&Qb[(q0 + 16 + c) * HD_ + 32 + g * 8]);

    // ---- pass 1: stage K per tile, QK^T + exp once, P~ -> regs ----
    unsigned int uA[8][2][2], uB[8][2][2];
    float lsumA = 0.f, lsumB = 0.f;
#pragma unroll
    for (int t8 = 0; t8 < 8; ++t8) {
        const int kt = t8 * 256;
        __syncthreads();
#pragma unroll
        for (int i = 0; i < 4; ++i) {
            const int eidx = (i * 512 + t) * 8;
            const int row = eidx >> 6, col = eidx & 63;
            const bf16x8 v = ldb8(&Kb[(size_t)(kt + row) * HD_ + col]);
            *reinterpret_cast<bf16x8*>(reinterpret_cast<char*>(sm.kv.K) +
                row * 128 + ((col * 2) ^ ((row & 7) << 4))) = v;
        }
        __syncthreads();
#pragma unroll
        for (int ss = 0; ss < 2; ++ss) {
            const int krow = kw + ss * 16 + c;
            const char* kbase = reinterpret_cast<const char*>(sm.kv.K) + krow * 128;
            const int sw = (krow & 7) << 4;
            const bf16x8 k0 = *reinterpret_cast<const bf16x8*>(kbase + ((g * 16) ^ sw));
            const bf16x8 k1 = *reinterpret_cast<const bf16x8*>(kbase + ((64 + g * 16) ^ sw));
            f32x4 aA = {}, aB = {};
            aA = mfma16(k0, aqA0, aA);
            aA = mfma16(k1, aqA1, aA);
            aB = mfma16(k0, aqB0, aB);
            aB = mfma16(k1, aqB1, aB);
            const float4 mk = *reinterpret_cast<const float4*>(&mrow[kt + kw + ss * 16 + g * 4]);
            const float pA0 = __expf(aA[0] * 0.125f + mk.x);
            const float pA1 = __expf(aA[1] * 0.125f + mk.y);
            const float pA2 = __expf(aA[2] * 0.125f + mk.z);
            const float pA3 = __expf(aA[3] * 0.125f + mk.w);
            const float pB0 = __expf(aB[0] * 0.125f + mk.x);
            const float pB1 = __expf(aB[1] * 0.125f + mk.y);
            const float pB2 = __expf(aB[2] * 0.125f + mk.z);
            const float pB3 = __expf(aB[3] * 0.125f + mk.w);
            lsumA += (pA0 + pA1) + (pA2 + pA3);
            lsumB += (pB0 + pB1) + (pB2 + pB3);
            union { __hip_bfloat16 hh[2]; unsigned int ui; } w0, w1;
            w0.hh[0] = __float2bfloat16(pA0); w0.hh[1] = __float2bfloat16(pA1);
            w1.hh[0] = __float2bfloat16(pA2); w1.hh[1] = __float2bfloat16(pA3);
            uA[t8][ss][0] = w0.ui; uA[t8][ss][1] = w1.ui;
            w0.hh[0] = __float2bfloat16(pB0); w0.hh[1] = __float2bfloat16(pB1);
            w1.hh[0] = __float2bfloat16(pB2); w1.hh[1] = __float2bfloat16(pB3);
            uB[t8][ss][0] = w0.ui; uB[t8][ss][1] = w1.ui;
        }
    }
    lsumA += __shfl_xor(lsumA, 16); lsumA += __shfl_xor(lsumA, 32);
    lsumB += __shfl_xor(lsumB, 16); lsumB += __shfl_xor(lsumB, 32);
    if (g == 0) { sred[w][c] = lsumA; sred[w][16 + c] = lsumB; }
    __syncthreads();
    float totA = 0.f, totB = 0.f;
#pragma unroll
    for (int w8 = 0; w8 < 8; ++w8) { totA += sred[w8][c]; totB += sred[w8][16 + c]; }
    const float invA = 1.0f / totA;
    const float invB = 1.0f / totB;
    if (w == 0 && g == 0) { invsh[c] = invA; invsh[16 + c] = invB; }

    // ---- pass 2: stage V per tile, probs stores from regs, PV ----
    f32x4 caccA[4] = {}, caccB[4] = {};
    float* prowA = probs + ((size_t)bh * S_ + q0 + c) * S_;
    float* prowB = prowA + (size_t)16 * S_;
    const int src0 = 32 * (g & 1) + c;
    const int src1 = src0 + 16;
    const int sigma = g >> 1;
#pragma unroll
    for (int t8 = 0; t8 < 8; ++t8) {
        const int kt = t8 * 256;
        __syncthreads();
#pragma unroll
        for (int i = 0; i < 4; ++i) {
            const int eidx = (i * 512 + t) * 8;
            const int row = eidx >> 8, col = eidx & 255;
            const bf16x8 v = ldb8(&Vb[(size_t)row * S_ + kt + col]);
            *reinterpret_cast<bf16x8*>(reinterpret_cast<char*>(sm.kv.V) +
                row * 512 + ((col * 2) ^ ((row & 7) << 4))) = v;
        }
        __syncthreads();
        // probs stores (float4 from regs)
#pragma unroll
        for (int ss = 0; ss < 2; ++ss) {
            f32x4 oA, oB;
            oA[0] = __uint_as_float(uA[t8][ss][0] << 16) * invA;
            oA[1] = __uint_as_float(uA[t8][ss][0] & 0xffff0000u) * invA;
            oA[2] = __uint_as_float(uA[t8][ss][1] << 16) * invA;
            oA[3] = __uint_as_float(uA[t8][ss][1] & 0xffff0000u) * invA;
            *reinterpret_cast<f32x4*>(&prowA[kt + kw + ss * 16 + g * 4]) = oA;
            oB[0] = __uint_as_float(uB[t8][ss][0] << 16) * invB;
            oB[1] = __uint_as_float(uB[t8][ss][0] & 0xffff0000u) * invB;
            oB[2] = __uint_as_float(uB[t8][ss][1] << 16) * invB;
            oB[3] = __uint_as_float(uB[t8][ss][1] & 0xffff0000u) * invB;
            *reinterpret_cast<f32x4*>(&prowB[kt + kw + ss * 16 + g * 4]) = oB;
        }
        // A-frags via shuffles: af.ui[jj] = u[t8][sigma][jj&1] from lane 32(g&1)+16(jj>>1)+c
        union { unsigned int ui[4]; bf16x8 v; } afA, afB;
        {
            const unsigned int x00 = __shfl(uA[t8][0][0], src0);
            const unsigned int x10 = __shfl(uA[t8][1][0], src0);
            const unsigned int x01 = __shfl(uA[t8][0][1], src0);
            const unsigned int x11 = __shfl(uA[t8][1][1], src0);
            const unsigned int x02 = __shfl(uA[t8][0][0], src1);
            const unsigned int x12 = __shfl(uA[t8][1][0], src1);
            const unsigned int x03 = __shfl(uA[t8][0][1], src1);
            const unsigned int x13 = __shfl(uA[t8][1][1], src1);
            afA.ui[0] = sigma ? x10 : x00;
            afA.ui[1] = sigma ? x11 : x01;
            afA.ui[2] = sigma ? x12 : x02;
            afA.ui[3] = sigma ? x13 : x03;
        }
        {
            const unsigned int x00 = __shfl(uB[t8][0][0], src0);
            const unsigned int x10 = __shfl(uB[t8][1][0], src0);
            const unsigned int x01 = __shfl(uB[t8][0][1], src0);
            const unsigned int x11 = __shfl(uB[t8][1][1], src0);
            const unsigned int x02 = __shfl(uB[t8][0][0], src1);
            const unsigned int x12 = __shfl(uB[t8][1][0], src1);
            const unsigned int x03 = __shfl(uB[t8][0][1], src1);
            const unsigned int x13 = __shfl(uB[t8][1][1], src1);
            afB.ui[0] = sigma ? x10 : x00;
            afB.ui[1] = sigma ? x11 : x01;
            afB.ui[2] = sigma ? x12 : x02;
            afB.ui[3] = sigma ? x13 : x03;
        }
        // PV from LDS V (swizzled): within-tile k-window byte base = 64*w
#pragma unroll
        for (int n = 0; n < 4; ++n) {
            const int vrow = n * 16 + c;
            const bf16x8 bv = *reinterpret_cast<const bf16x8*>(
                reinterpret_cast<const char*>(sm.kv.V) + vrow * 512 +
                ((64 * w + g * 16) ^ ((vrow & 7) << 4)));
            caccA[n] = mfma16(afA.v, bv, caccA[n]);
            caccB[n] = mfma16(afB.v, bv, caccB[n]);
        }
    }

    // ---- cross-wave PV reduce (LDS aliases kv -> barrier first) ----
    __syncthreads();
#pragma unroll
    for (int n = 0; n < 4; ++n)
#pragma unroll
        for (int r = 0; r < 4; ++r)
            sm.Cred[w][g * 4 + r][n * 16 + c] = caccA[n][r];
    __syncthreads();
    {
        const int row = t >> 5, col2 = (t & 31) * 2;
        float a0 = 0.f, a1 = 0.f;
#pragma unroll
        for (int w8 = 0; w8 < 8; ++w8) {
            const float2 vv = *reinterpret_cast<const float2*>(&sm.Cred[w8][row][col2]);
            a0 += vv.x; a1 += vv.y;
        }
        const float fin = invsh[row];
        union { __hip_bfloat16 hh[2]; unsigned int ui; } ov;
        ov.hh[0] = __float2bfloat16(a0 * fin);
        ov.hh[1] = __float2bfloat16(a1 * fin);
        *reinterpret_cast<unsigned int*>(
            &ctx[((size_t)b * S_ + q0 + row) * D_ + h * HD_ + col2]) = ov.ui;
    }
    __syncthreads();
#pragma unroll
    for (int n = 0; n < 4; ++n)
#pragma unroll
        for (int r = 0; r < 4; ++r)
            sm.Cred[w][g * 4 + r][n * 16 + c] = caccB[n][r];
    __syncthreads();
    {
        const int row = t >> 5, col2 = (t & 31) * 2;
        float a0 = 0.f, a1 = 0.f;
#pragma unroll
        for (int w8 = 0; w8 < 8; ++w8) {
            const float2 vv = *reinterpret_cast<const float2*>(&sm.Cred[w8][row][col2]);
            a0 += vv.x; a1 += vv.y;
        }
        const float fin = invsh[16 + row];
        union { __hip_bfloat16 hh[2]; unsigned int ui; } ov;
        ov.hh[0] = __float2bfloat16(a0 * fin);
        ov.hh[1] = __float2bfloat16(a1 * fin);
        *reinterpret_cast<unsigned int*>(
            &ctx[((size_t)b * S_ + q0 + 16 + row) * D_ + h * HD_ + col2]) = ov.ui;
    }
}

// ---------------- launch ----------------
extern "C" void kernel_launch(void* const* d_in, const int* in_sizes, int n_in,
                              void* d_out, int out_size, void* d_ws, size_t ws_size,
                              hipStream_t stream) {
    const float* hs   = (const float*)d_in[0];
    const float* mask = (const float*)d_in[1];
    const float* Wq   = (const float*)d_in[2];
    const float* bq   = (const float*)d_in[3];
    const float* Wk   = (const float*)d_in[4];
    const float* bk   = (const float*)d_in[5];
    const float* Wv   = (const float*)d_in[6];
    const float* bv   = (const float*)d_in[7];
    const float* Wo   = (const float*)d_in[8];
    const float* bo   = (const float*)d_in[9];

    float* out   = (float*)d_out;
    float* probs = out + (size_t)B_ * S_ * D_;

    const size_t MD = (size_t)B_ * S_ * D_;  // 4096*1024
    __hip_bfloat16* hsb   = (__hip_bfloat16*)d_ws;
    __hip_bfloat16* wqkvb = hsb + MD;
    __hip_bfloat16* wob   = wqkvb + 3u * 1024u * 1024u;
    __hip_bfloat16* Qh    = wob + (size_t)1024 * 1024;
    __hip_bfloat16* Kh    = Qh + MD;
    __hip_bfloat16* Vt    = Kh + MD;
    __hip_bfloat16* ctxb  = Vt + MD;

    conv_kernel<<<4096, 256, 0, stream>>>(hs, hsb, (int)(MD / 4));
    conv_kernel<<<1024, 256, 0, stream>>>(Wq, wqkvb, 262144);
    conv_kernel<<<1024, 256, 0, stream>>>(Wk, wqkvb + 1048576, 262144);
    conv_kernel<<<1024, 256, 0, stream>>>(Wv, wqkvb + 2097152, 262144);
    conv_kernel<<<1024, 256, 0, stream>>>(Wo, wob, 262144);

    gemm_bt<0><<<32 * 24, 256, 0, stream>>>(hsb, wqkvb, bq, bk, bv,
                                            Qh, Kh, Vt, nullptr, 4096, 3072, 1024);

    attn_kernel<<<B_ * H_ * (S_ / 32), 512, 0, stream>>>(Qh, Kh, Vt, mask, probs, ctxb);

    gemm_bt<1><<<32 * 8, 256, 0, stream>>>(ctxb, wob, bo, nullptr, nullptr,
                                           nullptr, nullptr, nullptr, out, 4096, 1024, 1024);
}

// Round 10
// 347.238 us; speedup vs baseline: 1.0882x; 1.0882x over previous
//
#include <hip/hip_runtime.h>
#include <hip/hip_bf16.h>

#define B_ 2
#define S_ 2048
#define D_ 1024
#define H_ 16
#define HD_ 64

typedef short bf16x8 __attribute__((ext_vector_type(8)));
typedef float f32x4 __attribute__((ext_vector_type(4)));

typedef __attribute__((address_space(3))) void lds_void;
typedef const __attribute__((address_space(1))) void gbl_void;

__device__ __forceinline__ f32x4 mfma16(bf16x8 a, bf16x8 b, f32x4 c) {
    return __builtin_amdgcn_mfma_f32_16x16x32_bf16(a, b, c, 0, 0, 0);
}

__device__ __forceinline__ bf16x8 ldb8(const __hip_bfloat16* p) {
    return *reinterpret_cast<const bf16x8*>(p);
}

// ---------------- fp32 -> bf16 conversion ----------------
__global__ __launch_bounds__(256) void conv_kernel(const float* __restrict__ src,
                                                   __hip_bfloat16* __restrict__ dst, int n4) {
    int i = blockIdx.x * 256 + threadIdx.x;
    if (i >= n4) return;
    float4 f = reinterpret_cast<const float4*>(src)[i];
    union { __hip_bfloat16 h[4]; ushort4 u; } cv;
    cv.h[0] = __float2bfloat16(f.x);
    cv.h[1] = __float2bfloat16(f.y);
    cv.h[2] = __float2bfloat16(f.z);
    cv.h[3] = __float2bfloat16(f.w);
    reinterpret_cast<ushort4*>(dst)[i] = cv.u;
}

// ---------------- GEMM (m97 structure): global_load_lds w16, linear LDS ----------------
// X: [M][K] bf16, Wt: [N][K] bf16. 128x128 tile, BK=32, 4 waves, 4x4 frags.
template <int MODE>
__global__ __launch_bounds__(256) void gemm_bt(
    const __hip_bfloat16* __restrict__ X, const __hip_bfloat16* __restrict__ Wt,
    const float* __restrict__ bias0, const float* __restrict__ bias1,
    const float* __restrict__ bias2,
    __hip_bfloat16* __restrict__ Yq, __hip_bfloat16* __restrict__ Yk,
    __hip_bfloat16* __restrict__ Yv, float* __restrict__ Yo,
    int M, int N, int K) {
    __shared__ __hip_bfloat16 As[128 * 32];   // linear: row*32 + col (global_load_lds order)
    __shared__ __hip_bfloat16 Bs[128 * 32];

    const int ntn = N >> 7;
    const int nwg = (M >> 7) * ntn;
    const int cpx = nwg >> 3;                 // nwg % 8 == 0 in all uses
    const int bid = blockIdx.x;
    const int lg = (bid & 7) * cpx + (bid >> 3);   // XCD-bijective swizzle
    const int tm = lg / ntn;
    const int tn = lg % ntn;
    const int t = threadIdx.x;
    const int w = t >> 6, l = t & 63, g = l >> 4, c = l & 15;
    const int wr = w >> 1, wc = w & 1;

    const int lrow16 = l >> 2;        // 0..15
    const int lcol = (l & 3) * 8;     // 0,8,16,24

    // wave w stages rows [w*32, w*32+32) of each tile in 2 instrs (16 rows each)
    const int r0 = w * 32 + lrow16;
    const int r1 = w * 32 + 16 + lrow16;
    const size_t xg0 = (size_t)(tm * 128 + r0) * K + lcol;
    const size_t xg1 = (size_t)(tm * 128 + r1) * K + lcol;
    const size_t wg0 = (size_t)(tn * 128 + r0) * K + lcol;
    const size_t wg1 = (size_t)(tn * 128 + r1) * K + lcol;

    f32x4 acc[4][4] = {};

    for (int k0 = 0; k0 < K; k0 += 32) {
        __syncthreads();
        __builtin_amdgcn_global_load_lds((gbl_void*)(X + xg0 + k0),
                                         (lds_void*)(As + (w * 32) * 32), 16, 0, 0);
        __builtin_amdgcn_global_load_lds((gbl_void*)(X + xg1 + k0),
                                         (lds_void*)(As + (w * 32 + 16) * 32), 16, 0, 0);
        __builtin_amdgcn_global_load_lds((gbl_void*)(Wt + wg0 + k0),
                                         (lds_void*)(Bs + (w * 32) * 32), 16, 0, 0);
        __builtin_amdgcn_global_load_lds((gbl_void*)(Wt + wg1 + k0),
                                         (lds_void*)(Bs + (w * 32 + 16) * 32), 16, 0, 0);
        __syncthreads();

        bf16x8 am[4], bn[4];
#pragma unroll
        for (int mi = 0; mi < 4; ++mi) am[mi] = ldb8(&As[(wr * 64 + mi * 16 + c) * 32 + g * 8]);
#pragma unroll
        for (int ni = 0; ni < 4; ++ni) bn[ni] = ldb8(&Bs[(wc * 64 + ni * 16 + c) * 32 + g * 8]);
#pragma unroll
        for (int mi = 0; mi < 4; ++mi)
#pragma unroll
            for (int ni = 0; ni < 4; ++ni)
                acc[mi][ni] = mfma16(am[mi], bn[ni], acc[mi][ni]);
    }

#pragma unroll
    for (int mi = 0; mi < 4; ++mi) {
        const int mbase = tm * 128 + wr * 64 + mi * 16 + g * 4;
#pragma unroll
        for (int ni = 0; ni < 4; ++ni) {
            const int n = tn * 128 + wc * 64 + ni * 16 + c;
#pragma unroll
            for (int r = 0; r < 4; ++r) {
                const int mm = mbase + r;
                float v = acc[mi][ni][r];
                if (MODE == 0) {
                    const float* bp = (n < 1024) ? bias0 : (n < 2048) ? bias1 : bias2;
                    const int nn = n & 1023;
                    v += bp[nn];
                    const int b = mm >> 11, s = mm & 2047;
                    const int h = nn >> 6, hd = nn & 63;
                    const size_t bh = (size_t)(b * H_ + h);
                    const __hip_bfloat16 bvv = __float2bfloat16(v);
                    if (n < 2048) {
                        __hip_bfloat16* dst = (n < 1024) ? Yq : Yk;
                        dst[(bh * S_ + s) * HD_ + hd] = bvv;
                    } else {
                        Yv[(bh * HD_ + hd) * S_ + s] = bvv;
                    }
                } else {
                    Yo[(size_t)mm * N + n] = v + bias0[n];
                }
            }
        }
    }
}

// ---------------- fused attention: shared k-tiles staged in LDS (r9) + XCD swizzle ----------------
__global__ __launch_bounds__(512) void attn_kernel(
    const __hip_bfloat16* __restrict__ Qh, const __hip_bfloat16* __restrict__ Kh,
    const __hip_bfloat16* __restrict__ Vt, const float* __restrict__ mask,
    float* __restrict__ probs, __hip_bfloat16* __restrict__ ctx) {
    union SMem {
        struct { __hip_bfloat16 K[256 * 64]; __hip_bfloat16 V[64 * 256]; } kv;  // 64 KB
        float Cred[8][16][68];
    };
    __shared__ SMem sm;
    __shared__ float sred[8][32];
    __shared__ float invsh[32];

    const int bid = blockIdx.x;
    const int lg = (bid & 7) * 256 + (bid >> 3);   // 2048 blocks, bijective XCD swizzle
    const int qt = lg & 63;          // S/32
    const int bh = lg >> 6;
    const int b = bh >> 4, h = bh & 15;
    const int t = threadIdx.x;
    const int w = t >> 6, l = t & 63, g = l >> 4, c = l & 15;
    const int q0 = qt * 32;
    const int kw = 32 * w;

    const __hip_bfloat16* Qb = Qh + (size_t)bh * S_ * HD_;
    const __hip_bfloat16* Kb = Kh + (size_t)bh * S_ * HD_;
    const __hip_bfloat16* Vb = Vt + (size_t)bh * HD_ * S_;
    const float* mrow = mask + (size_t)b * S_;

    const bf16x8 aqA0 = ldb8(&Qb[(q0 + c) * HD_ + g * 8]);
    const bf16x8 aqA1 = ldb8(&Qb[(q0 + c) * HD_ + 32 + g * 8]);
    const bf16x8 aqB0 = ldb8(&Qb[(q0 + 16 + c) * HD_ + g * 8]);
    const bf16x8 aqB1 = ldb8(&Qb[(q0 + 16 + c) * HD_ + 32 + g * 8]);

    // ---- pass 1: stage K per tile, QK^T + exp once, P~ -> regs ----
    unsigned int uA[8][2][2], uB[8][2][2];
    float lsumA = 0.f, lsumB = 0.f;
#pragma unroll
    for (int t8 = 0; t8 < 8; ++t8) {
        const int kt = t8 * 256;
        __syncthreads();
#pragma unroll
        for (int i = 0; i < 4; ++i) {
            const int eidx = (i * 512 + t) * 8;
            const int row = eidx >> 6, col = eidx & 63;
            const bf16x8 v = ldb8(&Kb[(size_t)(kt + row) * HD_ + col]);
            *reinterpret_cast<bf16x8*>(reinterpret_cast<char*>(sm.kv.K) +
                row * 128 + ((col * 2) ^ ((row & 7) << 4))) = v;
        }
        __syncthreads();
#pragma unroll
        for (int ss = 0; ss < 2; ++ss) {
            const int krow = kw + ss * 16 + c;
            const char* kbase = reinterpret_cast<const char*>(sm.kv.K) + krow * 128;
            const int sw = (krow & 7) << 4;
            const bf16x8 k0 = *reinterpret_cast<const bf16x8*>(kbase + ((g * 16) ^ sw));
            const bf16x8 k1 = *reinterpret_cast<const bf16x8*>(kbase + ((64 + g * 16) ^ sw));
            f32x4 aA = {}, aB = {};
            aA = mfma16(k0, aqA0, aA);
            aA = mfma16(k1, aqA1, aA);
            aB = mfma16(k0, aqB0, aB);
            aB = mfma16(k1, aqB1, aB);
            const float4 mk = *reinterpret_cast<const float4*>(&mrow[kt + kw + ss * 16 + g * 4]);
            const float pA0 = __expf(aA[0] * 0.125f + mk.x);
            const float pA1 = __expf(aA[1] * 0.125f + mk.y);
            const float pA2 = __expf(aA[2] * 0.125f + mk.z);
            const float pA3 = __expf(aA[3] * 0.125f + mk.w);
            const float pB0 = __expf(aB[0] * 0.125f + mk.x);
            const float pB1 = __expf(aB[1] * 0.125f + mk.y);
            const float pB2 = __expf(aB[2] * 0.125f + mk.z);
            const float pB3 = __expf(aB[3] * 0.125f + mk.w);
            lsumA += (pA0 + pA1) + (pA2 + pA3);
            lsumB += (pB0 + pB1) + (pB2 + pB3);
            union { __hip_bfloat16 hh[2]; unsigned int ui; } w0, w1;
            w0.hh[0] = __float2bfloat16(pA0); w0.hh[1] = __float2bfloat16(pA1);
            w1.hh[0] = __float2bfloat16(pA2); w1.hh[1] = __float2bfloat16(pA3);
            uA[t8][ss][0] = w0.ui; uA[t8][ss][1] = w1.ui;
            w0.hh[0] = __float2bfloat16(pB0); w0.hh[1] = __float2bfloat16(pB1);
            w1.hh[0] = __float2bfloat16(pB2); w1.hh[1] = __float2bfloat16(pB3);
            uB[t8][ss][0] = w0.ui; uB[t8][ss][1] = w1.ui;
        }
    }
    lsumA += __shfl_xor(lsumA, 16); lsumA += __shfl_xor(lsumA, 32);
    lsumB += __shfl_xor(lsumB, 16); lsumB += __shfl_xor(lsumB, 32);
    if (g == 0) { sred[w][c] = lsumA; sred[w][16 + c] = lsumB; }
    __syncthreads();
    float totA = 0.f, totB = 0.f;
#pragma unroll
    for (int w8 = 0; w8 < 8; ++w8) { totA += sred[w8][c]; totB += sred[w8][16 + c]; }
    const float invA = 1.0f / totA;
    const float invB = 1.0f / totB;
    if (w == 0 && g == 0) { invsh[c] = invA; invsh[16 + c] = invB; }

    // ---- pass 2: stage V per tile, probs stores from regs, PV ----
    f32x4 caccA[4] = {}, caccB[4] = {};
    float* prowA = probs + ((size_t)bh * S_ + q0 + c) * S_;
    float* prowB = prowA + (size_t)16 * S_;
    const int src0 = 32 * (g & 1) + c;
    const int src1 = src0 + 16;
    const int sigma = g >> 1;
#pragma unroll
    for (int t8 = 0; t8 < 8; ++t8) {
        const int kt = t8 * 256;
        __syncthreads();
#pragma unroll
        for (int i = 0; i < 4; ++i) {
            const int eidx = (i * 512 + t) * 8;
            const int row = eidx >> 8, col = eidx & 255;
            const bf16x8 v = ldb8(&Vb[(size_t)row * S_ + kt + col]);
            *reinterpret_cast<bf16x8*>(reinterpret_cast<char*>(sm.kv.V) +
                row * 512 + ((col * 2) ^ ((row & 7) << 4))) = v;
        }
        __syncthreads();
#pragma unroll
        for (int ss = 0; ss < 2; ++ss) {
            f32x4 oA, oB;
            oA[0] = __uint_as_float(uA[t8][ss][0] << 16) * invA;
            oA[1] = __uint_as_float(uA[t8][ss][0] & 0xffff0000u) * invA;
            oA[2] = __uint_as_float(uA[t8][ss][1] << 16) * invA;
            oA[3] = __uint_as_float(uA[t8][ss][1] & 0xffff0000u) * invA;
            *reinterpret_cast<f32x4*>(&prowA[kt + kw + ss * 16 + g * 4]) = oA;
            oB[0] = __uint_as_float(uB[t8][ss][0] << 16) * invB;
            oB[1] = __uint_as_float(uB[t8][ss][0] & 0xffff0000u) * invB;
            oB[2] = __uint_as_float(uB[t8][ss][1] << 16) * invB;
            oB[3] = __uint_as_float(uB[t8][ss][1] & 0xffff0000u) * invB;
            *reinterpret_cast<f32x4*>(&prowB[kt + kw + ss * 16 + g * 4]) = oB;
        }
        union { unsigned int ui[4]; bf16x8 v; } afA, afB;
        {
            const unsigned int x00 = __shfl(uA[t8][0][0], src0);
            const unsigned int x10 = __shfl(uA[t8][1][0], src0);
            const unsigned int x01 = __shfl(uA[t8][0][1], src0);
            const unsigned int x11 = __shfl(uA[t8][1][1], src0);
            const unsigned int x02 = __shfl(uA[t8][0][0], src1);
            const unsigned int x12 = __shfl(uA[t8][1][0], src1);
            const unsigned int x03 = __shfl(uA[t8][0][1], src1);
            const unsigned int x13 = __shfl(uA[t8][1][1], src1);
            afA.ui[0] = sigma ? x10 : x00;
            afA.ui[1] = sigma ? x11 : x01;
            afA.ui[2] = sigma ? x12 : x02;
            afA.ui[3] = sigma ? x13 : x03;
        }
        {
            const unsigned int x00 = __shfl(uB[t8][0][0], src0);
            const unsigned int x10 = __shfl(uB[t8][1][0], src0);
            const unsigned int x01 = __shfl(uB[t8][0][1], src0);
            const unsigned int x11 = __shfl(uB[t8][1][1], src0);
            const unsigned int x02 = __shfl(uB[t8][0][0], src1);
            const unsigned int x12 = __shfl(uB[t8][1][0], src1);
            const unsigned int x03 = __shfl(uB[t8][0][1], src1);
            const unsigned int x13 = __shfl(uB[t8][1][1], src1);
            afB.ui[0] = sigma ? x10 : x00;
            afB.ui[1] = sigma ? x11 : x01;
            afB.ui[2] = sigma ? x12 : x02;
            afB.ui[3] = sigma ? x13 : x03;
        }
#pragma unroll
        for (int n = 0; n < 4; ++n) {
            const int vrow = n * 16 + c;
            const bf16x8 bv = *reinterpret_cast<const bf16x8*>(
                reinterpret_cast<const char*>(sm.kv.V) + vrow * 512 +
                ((64 * w + g * 16) ^ ((vrow & 7) << 4)));
            caccA[n] = mfma16(afA.v, bv, caccA[n]);
            caccB[n] = mfma16(afB.v, bv, caccB[n]);
        }
    }

    // ---- cross-wave PV reduce ----
    __syncthreads();
#pragma unroll
    for (int n = 0; n < 4; ++n)
#pragma unroll
        for (int r = 0; r < 4; ++r)
            sm.Cred[w][g * 4 + r][n * 16 + c] = caccA[n][r];
    __syncthreads();
    {
        const int row = t >> 5, col2 = (t & 31) * 2;
        float a0 = 0.f, a1 = 0.f;
#pragma unroll
        for (int w8 = 0; w8 < 8; ++w8) {
            const float2 vv = *reinterpret_cast<const float2*>(&sm.Cred[w8][row][col2]);
            a0 += vv.x; a1 += vv.y;
        }
        const float fin = invsh[row];
        union { __hip_bfloat16 hh[2]; unsigned int ui; } ov;
        ov.hh[0] = __float2bfloat16(a0 * fin);
        ov.hh[1] = __float2bfloat16(a1 * fin);
        *reinterpret_cast<unsigned int*>(
            &ctx[((size_t)b * S_ + q0 + row) * D_ + h * HD_ + col2]) = ov.ui;
    }
    __syncthreads();
#pragma unroll
    for (int n = 0; n < 4; ++n)
#pragma unroll
        for (int r = 0; r < 4; ++r)
            sm.Cred[w][g * 4 + r][n * 16 + c] = caccB[n][r];
    __syncthreads();
    {
        const int row = t >> 5, col2 = (t & 31) * 2;
        float a0 = 0.f, a1 = 0.f;
#pragma unroll
        for (int w8 = 0; w8 < 8; ++w8) {
            const float2 vv = *reinterpret_cast<const float2*>(&sm.Cred[w8][row][col2]);
            a0 += vv.x; a1 += vv.y;
        }
        const float fin = invsh[16 + row];
        union { __hip_bfloat16 hh[2]; unsigned int ui; } ov;
        ov.hh[0] = __float2bfloat16(a0 * fin);
        ov.hh[1] = __float2bfloat16(a1 * fin);
        *reinterpret_cast<unsigned int*>(
            &ctx[((size_t)b * S_ + q0 + 16 + row) * D_ + h * HD_ + col2]) = ov.ui;
    }
}

// ---------------- launch ----------------
extern "C" void kernel_launch(void* const* d_in, const int* in_sizes, int n_in,
                              void* d_out, int out_size, void* d_ws, size_t ws_size,
                              hipStream_t stream) {
    const float* hs   = (const float*)d_in[0];
    const float* mask = (const float*)d_in[1];
    const float* Wq   = (const float*)d_in[2];
    const float* bq   = (const float*)d_in[3];
    const float* Wk   = (const float*)d_in[4];
    const float* bk   = (const float*)d_in[5];
    const float* Wv   = (const float*)d_in[6];
    const float* bv   = (const float*)d_in[7];
    const float* Wo   = (const float*)d_in[8];
    const float* bo   = (const float*)d_in[9];

    float* out   = (float*)d_out;
    float* probs = out + (size_t)B_ * S_ * D_;

    const size_t MD = (size_t)B_ * S_ * D_;  // 4096*1024
    __hip_bfloat16* hsb   = (__hip_bfloat16*)d_ws;
    __hip_bfloat16* wqkvb = hsb + MD;
    __hip_bfloat16* wob   = wqkvb + 3u * 1024u * 1024u;
    __hip_bfloat16* Qh    = wob + (size_t)1024 * 1024;
    __hip_bfloat16* Kh    = Qh + MD;
    __hip_bfloat16* Vt    = Kh + MD;
    __hip_bfloat16* ctxb  = Vt + MD;

    conv_kernel<<<4096, 256, 0, stream>>>(hs, hsb, (int)(MD / 4));
    conv_kernel<<<1024, 256, 0, stream>>>(Wq, wqkvb, 262144);
    conv_kernel<<<1024, 256, 0, stream>>>(Wk, wqkvb + 1048576, 262144);
    conv_kernel<<<1024, 256, 0, stream>>>(Wv, wqkvb + 2097152, 262144);
    conv_kernel<<<1024, 256, 0, stream>>>(Wo, wob, 262144);

    gemm_bt<0><<<32 * 24, 256, 0, stream>>>(hsb, wqkvb, bq, bk, bv,
                                            Qh, Kh, Vt, nullptr, 4096, 3072, 1024);

    attn_kernel<<<B_ * H_ * (S_ / 32), 512, 0, stream>>>(Qh, Kh, Vt, mask, probs, ctxb);

    gemm_bt<1><<<32 * 8, 256, 0, stream>>>(ctxb, wob, bo, nullptr, nullptr,
                                           nullptr, nullptr, nullptr, out, 4096, 1024, 1024);
}

// Round 11
// 325.754 us; speedup vs baseline: 1.1599x; 1.0660x over previous
//
#include <hip/hip_runtime.h>
#include <hip/hip_bf16.h>

#define B_ 2
#define S_ 2048
#define D_ 1024
#define H_ 16
#define HD_ 64

typedef short bf16x8 __attribute__((ext_vector_type(8)));
typedef float f32x4 __attribute__((ext_vector_type(4)));

typedef __attribute__((address_space(3))) void lds_void;
typedef const __attribute__((address_space(1))) void gbl_void;

__device__ __forceinline__ f32x4 mfma16(bf16x8 a, bf16x8 b, f32x4 c) {
    return __builtin_amdgcn_mfma_f32_16x16x32_bf16(a, b, c, 0, 0, 0);
}

__device__ __forceinline__ bf16x8 ldb8(const __hip_bfloat16* p) {
    return *reinterpret_cast<const bf16x8*>(p);
}

// ---------------- fp32 -> bf16 conversion ----------------
__global__ __launch_bounds__(256) void conv_kernel(const float* __restrict__ src,
                                                   __hip_bfloat16* __restrict__ dst, int n4) {
    int i = blockIdx.x * 256 + threadIdx.x;
    if (i >= n4) return;
    float4 f = reinterpret_cast<const float4*>(src)[i];
    union { __hip_bfloat16 h[4]; ushort4 u; } cv;
    cv.h[0] = __float2bfloat16(f.x);
    cv.h[1] = __float2bfloat16(f.y);
    cv.h[2] = __float2bfloat16(f.z);
    cv.h[3] = __float2bfloat16(f.w);
    reinterpret_cast<ushort4*>(dst)[i] = cv.u;
}

// ---------------- GEMM (m97 structure): global_load_lds w16, linear LDS ----------------
template <int MODE>
__global__ __launch_bounds__(256) void gemm_bt(
    const __hip_bfloat16* __restrict__ X, const __hip_bfloat16* __restrict__ Wt,
    const float* __restrict__ bias0, const float* __restrict__ bias1,
    const float* __restrict__ bias2,
    __hip_bfloat16* __restrict__ Yq, __hip_bfloat16* __restrict__ Yk,
    __hip_bfloat16* __restrict__ Yv, float* __restrict__ Yo,
    int M, int N, int K) {
    __shared__ __hip_bfloat16 As[128 * 32];
    __shared__ __hip_bfloat16 Bs[128 * 32];

    const int ntn = N >> 7;
    const int nwg = (M >> 7) * ntn;
    const int cpx = nwg >> 3;
    const int bid = blockIdx.x;
    const int lg = (bid & 7) * cpx + (bid >> 3);
    const int tm = lg / ntn;
    const int tn = lg % ntn;
    const int t = threadIdx.x;
    const int w = t >> 6, l = t & 63, g = l >> 4, c = l & 15;
    const int wr = w >> 1, wc = w & 1;

    const int lrow16 = l >> 2;
    const int lcol = (l & 3) * 8;

    const int r0 = w * 32 + lrow16;
    const int r1 = w * 32 + 16 + lrow16;
    const size_t xg0 = (size_t)(tm * 128 + r0) * K + lcol;
    const size_t xg1 = (size_t)(tm * 128 + r1) * K + lcol;
    const size_t wg0 = (size_t)(tn * 128 + r0) * K + lcol;
    const size_t wg1 = (size_t)(tn * 128 + r1) * K + lcol;

    f32x4 acc[4][4] = {};

    for (int k0 = 0; k0 < K; k0 += 32) {
        __syncthreads();
        __builtin_amdgcn_global_load_lds((gbl_void*)(X + xg0 + k0),
                                         (lds_void*)(As + (w * 32) * 32), 16, 0, 0);
        __builtin_amdgcn_global_load_lds((gbl_void*)(X + xg1 + k0),
                                         (lds_void*)(As + (w * 32 + 16) * 32), 16, 0, 0);
        __builtin_amdgcn_global_load_lds((gbl_void*)(Wt + wg0 + k0),
                                         (lds_void*)(Bs + (w * 32) * 32), 16, 0, 0);
        __builtin_amdgcn_global_load_lds((gbl_void*)(Wt + wg1 + k0),
                                         (lds_void*)(Bs + (w * 32 + 16) * 32), 16, 0, 0);
        __syncthreads();

        bf16x8 am[4], bn[4];
#pragma unroll
        for (int mi = 0; mi < 4; ++mi) am[mi] = ldb8(&As[(wr * 64 + mi * 16 + c) * 32 + g * 8]);
#pragma unroll
        for (int ni = 0; ni < 4; ++ni) bn[ni] = ldb8(&Bs[(wc * 64 + ni * 16 + c) * 32 + g * 8]);
#pragma unroll
        for (int mi = 0; mi < 4; ++mi)
#pragma unroll
            for (int ni = 0; ni < 4; ++ni)
                acc[mi][ni] = mfma16(am[mi], bn[ni], acc[mi][ni]);
    }

#pragma unroll
    for (int mi = 0; mi < 4; ++mi) {
        const int mbase = tm * 128 + wr * 64 + mi * 16 + g * 4;
#pragma unroll
        for (int ni = 0; ni < 4; ++ni) {
            const int n = tn * 128 + wc * 64 + ni * 16 + c;
#pragma unroll
            for (int r = 0; r < 4; ++r) {
                const int mm = mbase + r;
                float v = acc[mi][ni][r];
                if (MODE == 0) {
                    const float* bp = (n < 1024) ? bias0 : (n < 2048) ? bias1 : bias2;
                    const int nn = n & 1023;
                    v += bp[nn];
                    const int b = mm >> 11, s = mm & 2047;
                    const int h = nn >> 6, hd = nn & 63;
                    const size_t bh = (size_t)(b * H_ + h);
                    const __hip_bfloat16 bvv = __float2bfloat16(v);
                    if (n < 2048) {
                        __hip_bfloat16* dst = (n < 1024) ? Yq : Yk;
                        dst[(bh * S_ + s) * HD_ + hd] = bvv;
                    } else {
                        Yv[(bh * HD_ + hd) * S_ + s] = bvv;
                    }
                } else {
                    Yo[(size_t)mm * N + n] = v + bias0[n];
                }
            }
        }
    }
}

// K stage: linear gload_lds dest; source col pre-swizzled so LDS content matches
// layout byte(row*128 + (X ^ ((row&7)<<4))) = K[row][X/2].
#define STAGE_K(dstc, t8v) do {                                                   \
    const int kt_ = (t8v) * 256;                                                  \
    _Pragma("unroll")                                                             \
    for (int i_ = 0; i_ < 4; ++i_) {                                              \
        const int chunk_ = w * 4 + i_;                                            \
        const int row_ = 8 * chunk_ + (l >> 3);                                   \
        const int col_ = ((l & 7) ^ ((l >> 3) & 7)) * 8;                          \
        __builtin_amdgcn_global_load_lds(                                         \
            (gbl_void*)(Kb + (size_t)(kt_ + row_) * HD_ + col_),                  \
            (lds_void*)((dstc) + chunk_ * 1024), 16, 0, 0);                       \
    }                                                                             \
} while (0)

// V stage: layout byte(row*512 + (X ^ ((row&7)<<4))) = V[row][kt + X/2].
#define STAGE_V(dstc, t8v) do {                                                   \
    const int kt_ = (t8v) * 256;                                                  \
    _Pragma("unroll")                                                             \
    for (int i_ = 0; i_ < 4; ++i_) {                                              \
        const int chunk_ = w * 4 + i_;                                            \
        const int row_ = 2 * chunk_ + (l >> 5);                                   \
        const int col_ = ((l & 31) ^ (row_ & 7)) * 8;                             \
        __builtin_amdgcn_global_load_lds(                                         \
            (gbl_void*)(Vb + (size_t)row_ * S_ + kt_ + col_),                     \
            (lds_void*)((dstc) + chunk_ * 1024), 16, 0, 0);                       \
    }                                                                             \
} while (0)

// ---------------- fused attention: double-buffered pipelined staging ----------------
// 2048 blocks x 8 waves. Block owns 32 q-rows; wave w owns k-window [32w,32w+32)
// of each 256-k tile. K (pass1) / V (pass2) double-buffered via global_load_lds
// with counted vmcnt + RAW s_barrier (loads stay in flight across barriers).
__global__ __launch_bounds__(512) void attn_kernel(
    const __hip_bfloat16* __restrict__ Qh, const __hip_bfloat16* __restrict__ Kh,
    const __hip_bfloat16* __restrict__ Vt, const float* __restrict__ mask,
    float* __restrict__ probs, __hip_bfloat16* __restrict__ ctx) {
    union SMem {
        char Kdb[2][32768];      // K/V tile double-buffer (64 KB)
        float Cred[8][16][68];   // epilogue reduce (aliases)
    };
    __shared__ SMem sm;
    __shared__ float msk[2048];
    __shared__ float sred[8][32];
    __shared__ float invsh[32];

    const int bid = blockIdx.x;
    const int lg = (bid & 7) * 256 + (bid >> 3);
    const int qt = lg & 63;
    const int bh = lg >> 6;
    const int b = bh >> 4, h = bh & 15;
    const int t = threadIdx.x;
    const int w = t >> 6, l = t & 63, g = l >> 4, c = l & 15;
    const int q0 = qt * 32;
    const int kw = 32 * w;

    const __hip_bfloat16* Qb = Qh + (size_t)bh * S_ * HD_;
    const __hip_bfloat16* Kb = Kh + (size_t)bh * S_ * HD_;
    const __hip_bfloat16* Vb = Vt + (size_t)bh * HD_ * S_;
    const float* mrow = mask + (size_t)b * S_;

    // mask -> LDS once (keeps per-iter global loads out of the vmcnt queue)
    *reinterpret_cast<float4*>(&msk[t * 4]) =
        *reinterpret_cast<const float4*>(&mrow[t * 4]);

    const bf16x8 aqA0 = ldb8(&Qb[(q0 + c) * HD_ + g * 8]);
    const bf16x8 aqA1 = ldb8(&Qb[(q0 + c) * HD_ + 32 + g * 8]);
    const bf16x8 aqB0 = ldb8(&Qb[(q0 + 16 + c) * HD_ + g * 8]);
    const bf16x8 aqB1 = ldb8(&Qb[(q0 + 16 + c) * HD_ + 32 + g * 8]);

    unsigned int uA[8][2][2], uB[8][2][2];
    float lsumA = 0.f, lsumB = 0.f;

    // ---- pass 1: pipelined K tiles, QK^T + exp, P~ -> regs ----
    STAGE_K(sm.Kdb[0], 0);
#pragma unroll
    for (int t8 = 0; t8 < 8; ++t8) {
        char* cur = sm.Kdb[t8 & 1];
        if (t8 < 7) {
            STAGE_K(sm.Kdb[(t8 & 1) ^ 1], t8 + 1);
            asm volatile("s_waitcnt vmcnt(4)" ::: "memory");
        } else {
            asm volatile("s_waitcnt vmcnt(0)" ::: "memory");
        }
        if (t8 == 0) asm volatile("s_waitcnt lgkmcnt(0)" ::: "memory");
        __builtin_amdgcn_s_barrier();
        __builtin_amdgcn_sched_barrier(0);
        const int kt = t8 * 256;
#pragma unroll
        for (int ss = 0; ss < 2; ++ss) {
            const int krow = kw + ss * 16 + c;
            const char* kb2 = cur + krow * 128;
            const int sw = (krow & 7) << 4;
            const bf16x8 k0 = *reinterpret_cast<const bf16x8*>(kb2 + ((g * 16) ^ sw));
            const bf16x8 k1 = *reinterpret_cast<const bf16x8*>(kb2 + ((64 + g * 16) ^ sw));
            f32x4 aA = {}, aB = {};
            aA = mfma16(k0, aqA0, aA);
            aA = mfma16(k1, aqA1, aA);
            aB = mfma16(k0, aqB0, aB);
            aB = mfma16(k1, aqB1, aB);
            const float4 mk = *reinterpret_cast<const float4*>(&msk[kt + kw + ss * 16 + g * 4]);
            const float pA0 = __expf(aA[0] * 0.125f + mk.x);
            const float pA1 = __expf(aA[1] * 0.125f + mk.y);
            const float pA2 = __expf(aA[2] * 0.125f + mk.z);
            const float pA3 = __expf(aA[3] * 0.125f + mk.w);
            const float pB0 = __expf(aB[0] * 0.125f + mk.x);
            const float pB1 = __expf(aB[1] * 0.125f + mk.y);
            const float pB2 = __expf(aB[2] * 0.125f + mk.z);
            const float pB3 = __expf(aB[3] * 0.125f + mk.w);
            lsumA += (pA0 + pA1) + (pA2 + pA3);
            lsumB += (pB0 + pB1) + (pB2 + pB3);
            union { __hip_bfloat16 hh[2]; unsigned int ui; } w0, w1;
            w0.hh[0] = __float2bfloat16(pA0); w0.hh[1] = __float2bfloat16(pA1);
            w1.hh[0] = __float2bfloat16(pA2); w1.hh[1] = __float2bfloat16(pA3);
            uA[t8][ss][0] = w0.ui; uA[t8][ss][1] = w1.ui;
            w0.hh[0] = __float2bfloat16(pB0); w0.hh[1] = __float2bfloat16(pB1);
            w1.hh[0] = __float2bfloat16(pB2); w1.hh[1] = __float2bfloat16(pB3);
            uB[t8][ss][0] = w0.ui; uB[t8][ss][1] = w1.ui;
        }
        __builtin_amdgcn_sched_barrier(0);
        __builtin_amdgcn_s_barrier();
    }
    lsumA += __shfl_xor(lsumA, 16); lsumA += __shfl_xor(lsumA, 32);
    lsumB += __shfl_xor(lsumB, 16); lsumB += __shfl_xor(lsumB, 32);
    if (g == 0) { sred[w][c] = lsumA; sred[w][16 + c] = lsumB; }
    __syncthreads();
    float totA = 0.f, totB = 0.f;
#pragma unroll
    for (int w8 = 0; w8 < 8; ++w8) { totA += sred[w8][c]; totB += sred[w8][16 + c]; }
    const float invA = 1.0f / totA;
    const float invB = 1.0f / totB;
    if (w == 0 && g == 0) { invsh[c] = invA; invsh[16 + c] = invB; }

    // ---- pass 2: pipelined V tiles, probs stores, PV ----
    f32x4 caccA[4] = {}, caccB[4] = {};
    float* prowA = probs + ((size_t)bh * S_ + q0 + c) * S_;
    float* prowB = prowA + (size_t)16 * S_;
    const int src0 = 32 * (g & 1) + c;
    const int src1 = src0 + 16;
    const int sigma = g >> 1;
    STAGE_V(sm.Kdb[0], 0);
#pragma unroll
    for (int t8 = 0; t8 < 8; ++t8) {
        char* cur = sm.Kdb[t8 & 1];
        if (t8 < 7) STAGE_V(sm.Kdb[(t8 & 1) ^ 1], t8 + 1);
        if (t8 == 0 || t8 == 7) asm volatile("s_waitcnt vmcnt(4)" ::: "memory");
        else                    asm volatile("s_waitcnt vmcnt(8)" ::: "memory");
        if (t8 == 0) asm volatile("s_waitcnt lgkmcnt(0)" ::: "memory");
        __builtin_amdgcn_s_barrier();
        __builtin_amdgcn_sched_barrier(0);
        const int kt = t8 * 256;
#pragma unroll
        for (int ss = 0; ss < 2; ++ss) {
            f32x4 oA, oB;
            oA[0] = __uint_as_float(uA[t8][ss][0] << 16) * invA;
            oA[1] = __uint_as_float(uA[t8][ss][0] & 0xffff0000u) * invA;
            oA[2] = __uint_as_float(uA[t8][ss][1] << 16) * invA;
            oA[3] = __uint_as_float(uA[t8][ss][1] & 0xffff0000u) * invA;
            *reinterpret_cast<f32x4*>(&prowA[kt + kw + ss * 16 + g * 4]) = oA;
            oB[0] = __uint_as_float(uB[t8][ss][0] << 16) * invB;
            oB[1] = __uint_as_float(uB[t8][ss][0] & 0xffff0000u) * invB;
            oB[2] = __uint_as_float(uB[t8][ss][1] << 16) * invB;
            oB[3] = __uint_as_float(uB[t8][ss][1] & 0xffff0000u) * invB;
            *reinterpret_cast<f32x4*>(&prowB[kt + kw + ss * 16 + g * 4]) = oB;
        }
        union { unsigned int ui[4]; bf16x8 v; } afA, afB;
        {
            const unsigned int x00 = __shfl(uA[t8][0][0], src0);
            const unsigned int x10 = __shfl(uA[t8][1][0], src0);
            const unsigned int x01 = __shfl(uA[t8][0][1], src0);
            const unsigned int x11 = __shfl(uA[t8][1][1], src0);
            const unsigned int x02 = __shfl(uA[t8][0][0], src1);
            const unsigned int x12 = __shfl(uA[t8][1][0], src1);
            const unsigned int x03 = __shfl(uA[t8][0][1], src1);
            const unsigned int x13 = __shfl(uA[t8][1][1], src1);
            afA.ui[0] = sigma ? x10 : x00;
            afA.ui[1] = sigma ? x11 : x01;
            afA.ui[2] = sigma ? x12 : x02;
            afA.ui[3] = sigma ? x13 : x03;
        }
        {
            const unsigned int x00 = __shfl(uB[t8][0][0], src0);
            const unsigned int x10 = __shfl(uB[t8][1][0], src0);
            const unsigned int x01 = __shfl(uB[t8][0][1], src0);
            const unsigned int x11 = __shfl(uB[t8][1][1], src0);
            const unsigned int x02 = __shfl(uB[t8][0][0], src1);
            const unsigned int x12 = __shfl(uB[t8][1][0], src1);
            const unsigned int x03 = __shfl(uB[t8][0][1], src1);
            const unsigned int x13 = __shfl(uB[t8][1][1], src1);
            afB.ui[0] = sigma ? x10 : x00;
            afB.ui[1] = sigma ? x11 : x01;
            afB.ui[2] = sigma ? x12 : x02;
            afB.ui[3] = sigma ? x13 : x03;
        }
#pragma unroll
        for (int n = 0; n < 4; ++n) {
            const int vrow = n * 16 + c;
            const bf16x8 bv = *reinterpret_cast<const bf16x8*>(
                cur + vrow * 512 + ((64 * w + g * 16) ^ ((vrow & 7) << 4)));
            caccA[n] = mfma16(afA.v, bv, caccA[n]);
            caccB[n] = mfma16(afB.v, bv, caccB[n]);
        }
        __builtin_amdgcn_sched_barrier(0);
        __builtin_amdgcn_s_barrier();
    }

    // ---- cross-wave PV reduce (full drain ok; pipeline over) ----
    __syncthreads();
#pragma unroll
    for (int n = 0; n < 4; ++n)
#pragma unroll
        for (int r = 0; r < 4; ++r)
            sm.Cred[w][g * 4 + r][n * 16 + c] = caccA[n][r];
    __syncthreads();
    {
        const int row = t >> 5, col2 = (t & 31) * 2;
        float a0 = 0.f, a1 = 0.f;
#pragma unroll
        for (int w8 = 0; w8 < 8; ++w8) {
            const float2 vv = *reinterpret_cast<const float2*>(&sm.Cred[w8][row][col2]);
            a0 += vv.x; a1 += vv.y;
        }
        const float fin = invsh[row];
        union { __hip_bfloat16 hh[2]; unsigned int ui; } ov;
        ov.hh[0] = __float2bfloat16(a0 * fin);
        ov.hh[1] = __float2bfloat16(a1 * fin);
        *reinterpret_cast<unsigned int*>(
            &ctx[((size_t)b * S_ + q0 + row) * D_ + h * HD_ + col2]) = ov.ui;
    }
    __syncthreads();
#pragma unroll
    for (int n = 0; n < 4; ++n)
#pragma unroll
        for (int r = 0; r < 4; ++r)
            sm.Cred[w][g * 4 + r][n * 16 + c] = caccB[n][r];
    __syncthreads();
    {
        const int row = t >> 5, col2 = (t & 31) * 2;
        float a0 = 0.f, a1 = 0.f;
#pragma unroll
        for (int w8 = 0; w8 < 8; ++w8) {
            const float2 vv = *reinterpret_cast<const float2*>(&sm.Cred[w8][row][col2]);
            a0 += vv.x; a1 += vv.y;
        }
        const float fin = invsh[16 + row];
        union { __hip_bfloat16 hh[2]; unsigned int ui; } ov;
        ov.hh[0] = __float2bfloat16(a0 * fin);
        ov.hh[1] = __float2bfloat16(a1 * fin);
        *reinterpret_cast<unsigned int*>(
            &ctx[((size_t)b * S_ + q0 + 16 + row) * D_ + h * HD_ + col2]) = ov.ui;
    }
}

// ---------------- launch ----------------
extern "C" void kernel_launch(void* const* d_in, const int* in_sizes, int n_in,
                              void* d_out, int out_size, void* d_ws, size_t ws_size,
                              hipStream_t stream) {
    const float* hs   = (const float*)d_in[0];
    const float* mask = (const float*)d_in[1];
    const float* Wq   = (const float*)d_in[2];
    const float* bq   = (const float*)d_in[3];
    const float* Wk   = (const float*)d_in[4];
    const float* bk   = (const float*)d_in[5];
    const float* Wv   = (const float*)d_in[6];
    const float* bv   = (const float*)d_in[7];
    const float* Wo   = (const float*)d_in[8];
    const float* bo   = (const float*)d_in[9];

    float* out   = (float*)d_out;
    float* probs = out + (size_t)B_ * S_ * D_;

    const size_t MD = (size_t)B_ * S_ * D_;
    __hip_bfloat16* hsb   = (__hip_bfloat16*)d_ws;
    __hip_bfloat16* wqkvb = hsb + MD;
    __hip_bfloat16* wob   = wqkvb + 3u * 1024u * 1024u;
    __hip_bfloat16* Qh    = wob + (size_t)1024 * 1024;
    __hip_bfloat16* Kh    = Qh + MD;
    __hip_bfloat16* Vt    = Kh + MD;
    __hip_bfloat16* ctxb  = Vt + MD;

    conv_kernel<<<4096, 256, 0, stream>>>(hs, hsb, (int)(MD / 4));
    conv_kernel<<<1024, 256, 0, stream>>>(Wq, wqkvb, 262144);
    conv_kernel<<<1024, 256, 0, stream>>>(Wk, wqkvb + 1048576, 262144);
    conv_kernel<<<1024, 256, 0, stream>>>(Wv, wqkvb + 2097152, 262144);
    conv_kernel<<<1024, 256, 0, stream>>>(Wo, wob, 262144);

    gemm_bt<0><<<32 * 24, 256, 0, stream>>>(hsb, wqkvb, bq, bk, bv,
                                            Qh, Kh, Vt, nullptr, 4096, 3072, 1024);

    attn_kernel<<<B_ * H_ * (S_ / 32), 512, 0, stream>>>(Qh, Kh, Vt, mask, probs, ctxb);

    gemm_bt<1><<<32 * 8, 256, 0, stream>>>(ctxb, wob, bo, nullptr, nullptr,
                                           nullptr, nullptr, nullptr, out, 4096, 1024, 1024);
}